// Round 4
// baseline (486.515 us; speedup 1.0000x reference)
//
#include <hip/hip_runtime.h>
#include <stdint.h>

#define BB 64
#define CC 80
#define TT 16384
#define NB 2048      // linear buckets over [-4,4], width 1/256
#define CAP 1024     // candidate capacity (expected ~80-150 used)
#define NT 256       // threads per block
#define VPT 16       // float4 per thread: TT/4/NT

// Linear bucket: floor(v*256)+1024, clamped to [0, NB-1]. Monotone in v.
__device__ __forceinline__ int bucket_of(float v) {
    float bf = fmaf(v, 256.0f, 1024.0f);
    bf = fminf(fmaxf(bf, 0.0f), 2047.0f);
    return (int)bf;
}

extern "C" __global__ __launch_bounds__(NT)
void statpool(const float* __restrict__ x, const int* __restrict__ lengths,
              float* __restrict__ out) {
    const int row = blockIdx.x;           // 0 .. B*C-1
    const int b   = row / CC;
    const int c   = row % CC;
    const float* __restrict__ xr = x + (size_t)row * TT;
    const int L   = lengths[b];           // in [T/2, T] => nfull >= 2048
    const int tid = threadIdx.x;
    const int lane = tid & 63;
    const int wid  = tid >> 6;

    __shared__ uint32_t hist[NB];         // histogram -> inclusive CDF (8 KB)
    __shared__ uint2    candp[CAP];       // .x = value bits, .y = bucket (8 KB)
    __shared__ uint32_t tsum[NT];         // scan partials (1 KB)
    __shared__ float    wsum[4], wsq[4];
    __shared__ int      rbkt[6], rwr[6];
    __shared__ float    res[6];
    __shared__ float    wts[3];
    __shared__ uint32_t ccount;

    // ---- Issue global loads FIRST; hist zeroing overlaps their latency ----
    const int nfull = L >> 2;
    const float4* x4 = (const float4*)xr;
    float4 v4[VPT];
    #pragma unroll
    for (int i = 0; i < 8; i++) v4[i] = x4[tid + i * NT];   // idx < 2048 <= nfull
    #pragma unroll
    for (int i = 8; i < VPT; i++) {
        int idx = tid + i * NT;
        v4[i] = make_float4(0.f, 0.f, 0.f, 0.f);
        if (idx < nfull) v4[i] = x4[idx];
    }
    float tailv = 0.f;
    const bool hasTail = tid < (L & 3);
    if (hasTail) tailv = xr[(L & ~3) + tid];

    for (int i = tid; i < NB; i += NT) hist[i] = 0u;
    if (tid == 0) ccount = 0u;
    __syncthreads();

    // ---- Pass 1: histogram + moments from registers ----
    float sum = 0.f, sq = 0.f;
    #pragma unroll
    for (int i = 0; i < VPT; i++) {
        int idx = tid + i * NT;
        if (i < 8 || idx < nfull) {
            float4 v = v4[i];
            sum += v.x + v.y + v.z + v.w;
            sq  = fmaf(v.x, v.x, fmaf(v.y, v.y, fmaf(v.z, v.z, fmaf(v.w, v.w, sq))));
            atomicAdd(&hist[bucket_of(v.x)], 1u);
            atomicAdd(&hist[bucket_of(v.y)], 1u);
            atomicAdd(&hist[bucket_of(v.z)], 1u);
            atomicAdd(&hist[bucket_of(v.w)], 1u);
        }
    }
    if (hasTail) {
        sum += tailv; sq = fmaf(tailv, tailv, sq);
        atomicAdd(&hist[bucket_of(tailv)], 1u);
    }
    for (int off = 32; off > 0; off >>= 1) {
        sum += __shfl_down(sum, off);
        sq  += __shfl_down(sq,  off);
    }
    if (lane == 0) { wsum[wid] = sum; wsq[wid] = sq; }
    __syncthreads();

    // ---- Scan: per-thread partial over 8 entries, then 1-wave shfl scan ----
    const int base = tid * (NB / NT);
    {
        uint32_t s = 0;
        #pragma unroll
        for (int i = 0; i < NB / NT; i++) s += hist[base + i];
        tsum[tid] = s;
    }
    __syncthreads();

    if (tid < 64) {
        uint32_t a0 = tsum[4*tid+0], a1 = tsum[4*tid+1],
                 a2 = tsum[4*tid+2], a3 = tsum[4*tid+3];
        uint32_t tot = a0 + a1 + a2 + a3;
        uint32_t inc = tot;
        #pragma unroll
        for (int off = 1; off < 64; off <<= 1) {
            uint32_t t = __shfl_up(inc, off);
            if (tid >= off) inc += t;
        }
        uint32_t ex = inc - tot;
        tsum[4*tid+0] = ex;
        tsum[4*tid+1] = ex + a0;
        tsum[4*tid+2] = ex + a0 + a1;
        tsum[4*tid+3] = ex + a0 + a1 + a2;
    } else if (tid == 64) {
        // mean/std on a parallel wave
        float fs = wsum[0] + wsum[1] + wsum[2] + wsum[3];
        float fq = wsq[0]  + wsq[1]  + wsq[2]  + wsq[3];
        float denom = (float)L;                 // L >= 8192 > EPS
        float mean = fs / denom;
        float var  = fq / denom - mean * mean;
        float stdv = sqrtf(fmaxf(var, 1e-6f));
        out[(size_t)b * (5*CC) + 0*CC + c] = mean;
        out[(size_t)b * (5*CC) + 1*CC + c] = stdv;
    }
    __syncthreads();

    {
        uint32_t run = tsum[tid];
        #pragma unroll
        for (int i = 0; i < NB / NT; i++) { run += hist[base + i]; hist[base + i] = run; }
    }
    __syncthreads();

    // ---- Rank -> bucket via binary search on inclusive CDF ----
    if (tid < 6) {
        const float qs3[3] = {0.25f, 0.5f, 0.75f};
        const int qi = tid >> 1;
        float pos = qs3[qi] * (float)(L - 1);   // fp32, same as reference
        int r = (tid & 1) ? (int)ceilf(pos) : (int)floorf(pos);
        if ((tid & 1) == 0) wts[qi] = pos - floorf(pos);
        int lo = 0, hi = NB - 1;
        while (lo < hi) {
            int mid = (lo + hi) >> 1;
            if (hist[mid] > (uint32_t)r) hi = mid; else lo = mid + 1;
        }
        rbkt[tid] = lo;
        rwr[tid]  = r - (int)(lo ? hist[lo - 1] : 0u);
    }
    __syncthreads();

    const int b0 = rbkt[0], b1 = rbkt[1], b2 = rbkt[2],
              b3 = rbkt[3], b4 = rbkt[4], b5 = rbkt[5];
    const int t0 = rwr[0], t1 = rwr[1], t2 = rwr[2],
              t3 = rwr[3], t4 = rwr[4], t5 = rwr[5];

    // ---- Pass 2: gather candidates FROM REGISTERS (no memory re-read) ----
    auto gthr = [&](float f) {
        int bk = bucket_of(f);
        bool hit = (bk >= b0 && bk <= b1) || (bk >= b2 && bk <= b3) ||
                   (bk >= b4 && bk <= b5);
        if (hit) {
            uint32_t p = atomicAdd(&ccount, 1u);
            if (p < CAP) candp[p] = make_uint2(__float_as_uint(f), (uint32_t)bk);
        }
    };
    #pragma unroll
    for (int i = 0; i < VPT; i++) {
        int idx = tid + i * NT;
        if (i < 8 || idx < nfull) {
            float4 v = v4[i];
            gthr(v.x); gthr(v.y); gthr(v.z); gthr(v.w);
        }
    }
    if (hasTail) gthr(tailv);
    __syncthreads();

    // ---- Rank-by-counting selection (replaces bitonic sort; 2 barriers) ----
    // All elements of each target bucket are in candp, so within-bucket rank
    // of candidate i = count of same-bucket candidates ordered before it
    // (value order, index tie-break => consistent total order == stable sort).
    const int m = (int)(ccount < (uint32_t)CAP ? ccount : (uint32_t)CAP);
    for (int i = tid; i < m; i += NT) {
        uint2 ci = candp[i];
        float vi = __uint_as_float(ci.x);
        int   bi = (int)ci.y;
        int cnt = 0;
        for (int j = 0; j < m; j++) {
            uint2 cj = candp[j];                 // broadcast read, conflict-free
            float vj = __uint_as_float(cj.x);
            bool before = ((int)cj.y == bi) &&
                          (vj < vi || (vj == vi && j < i));
            cnt += before ? 1 : 0;
        }
        if (bi == b0 && cnt == t0) res[0] = vi;
        if (bi == b1 && cnt == t1) res[1] = vi;
        if (bi == b2 && cnt == t2) res[2] = vi;
        if (bi == b3 && cnt == t3) res[3] = vi;
        if (bi == b4 && cnt == t4) res[4] = vi;
        if (bi == b5 && cnt == t5) res[5] = vi;
    }
    __syncthreads();

    if (tid < 3) {
        float xlo = res[2*tid], xhi = res[2*tid+1];
        out[(size_t)b * (5*CC) + (2 + tid) * CC + c] = xlo + wts[tid] * (xhi - xlo);
    }
}

extern "C" void kernel_launch(void* const* d_in, const int* in_sizes, int n_in,
                              void* d_out, int out_size, void* d_ws, size_t ws_size,
                              hipStream_t stream) {
    (void)in_sizes; (void)n_in; (void)out_size; (void)d_ws; (void)ws_size;
    const float* x       = (const float*)d_in[0];
    const int*   lengths = (const int*)d_in[1];
    float*       out     = (float*)d_out;
    hipLaunchKernelGGL(statpool, dim3(BB * CC), dim3(NT), 0, stream, x, lengths, out);
}